// Round 12
// baseline (845.443 us; speedup 1.0000x reference)
//
#include <hip/hip_runtime.h>
#include <math.h>

// Problem constants
#define ST 64      // sequence length T
#define NBAT 64    // batch B
#define ED 256     // embedding dim E
#define HD 512     // hidden dim H
#define G4 2048    // 4*H
#define VO 32000   // vocab
#define NWORK 64               // recurrence blocks
#define NLOG 192               // logits worker blocks
#define NTILES (VO / 128)      // 250 vocab n-tiles
#define SLOT32 (NBAT * HD / 2) // u32s per h slot (64 KB)

typedef unsigned int u32;
typedef __bf16 bf16;
typedef bf16 bf16x8 __attribute__((ext_vector_type(8)));
typedef float f32x4 __attribute__((ext_vector_type(4)));

__device__ __forceinline__ float sigm(float x) { return 1.f / (1.f + expf(-x)); }

// ---------------- prep kernels ----------------

__global__ void k_lengths(const int* __restrict__ toks, int* __restrict__ len) {
  int b = threadIdx.x;
  if (b < NBAT) {
    int n = 0;
    for (int t = 0; t < ST; ++t) n += (toks[b * ST + t] != 0) ? 1 : 0;
    len[b] = n;
  }
}

__global__ void k_cast(const float* __restrict__ src, bf16* __restrict__ dst, int n) {
  int i = blockIdx.x * blockDim.x + threadIdx.x;
  if (i < n) dst[i] = (bf16)src[i];
}

__global__ void k_bias(const float* __restrict__ a, const float* __restrict__ b,
                       float* __restrict__ o) {
  int i = blockIdx.x * blockDim.x + threadIdx.x;
  if (i < G4) o[i] = a[i] + b[i];
}

// encX[t][b][e] = emb[toks[b][t]][e]; decX[t][b][e] = emb[t==0 ? 1 : toks[b][t-1]][e]
__global__ void k_gather(const int* __restrict__ toks, const float* __restrict__ emb,
                         bf16* __restrict__ encX, bf16* __restrict__ decX) {
  int i = blockIdx.x * blockDim.x + threadIdx.x;
  if (i >= ST * NBAT * ED) return;
  int e = i % ED;
  int tb = i / ED;
  int b = tb % NBAT;
  int t = tb / NBAT;
  int te = toks[b * ST + t];
  encX[i] = (bf16)emb[te * ED + e];
  int td = (t == 0) ? 1 : toks[b * ST + t - 1];
  decX[i] = (bf16)emb[td * ED + e];
}

// ---------------- fused persistent kernel ----------------
//
// 256 blocks, 1 per CU. Blocks 0..63: r10 recurrence. Blocks 64..255:
// logits workers on the otherwise-idle CUs.
//
// Recurrence sync (unchanged): full-line bypass h-stores to per-step
// slots; __syncthreads drains acks; tid0 fires flags[blk]=step+1 for ALL
// steps. Wave0 polls the 64 dense flags (sleep 1 -- latency-critical),
// LDS-bounces go to waves 1-7. Block0's wave0 publishes decgo=step.
//
// Logits workers: poll decgo with s_sleep(64) (~1.7 us period). r11 used
// sleep(8) -> 192 pollers hammered the decgo line every ~0.2 us, congesting
// the coherence point the recurrence fire/detect chain lives on (r7/r8
// lesson: poller rate is the lever; cadence degraded 5.2 -> 6.1 us/step).
// Workers need only ~0.5 us compute per ~6 us step -> 1.7 us extra lag is
// free. Everything else identical to r11.
__global__ __launch_bounds__(512, 2) void k_fused(
    const bf16* __restrict__ encX, const bf16* __restrict__ decX,
    const bf16* __restrict__ WihE, const bf16* __restrict__ WhhE,
    const bf16* __restrict__ WihD, const bf16* __restrict__ WhhD,
    const float* __restrict__ bsumE, const float* __restrict__ bsumD,
    const int* __restrict__ len,
    const bf16* __restrict__ WbL, const float* __restrict__ linb,
    float* __restrict__ out,
    u32* __restrict__ hx32,    // [2*ST+1][NWORK][NBAT][8/2] per-step h slots
    u32* flags,                // [64] dense worker progress
    u32* decgo)                // [1] block0 broadcast of confirmed step
{
  __shared__ __align__(16) char smem[133632];

  const int tid  = threadIdx.x;
  const int lane = tid & 63;
  const int wid  = tid >> 6;
  const int blk  = blockIdx.x;
  const int r16  = lane & 15;
  const int kh   = lane >> 4;
  const int kc   = kh * 8;

  if (blk < NWORK) {
    // ================= recurrence block =================
    auto Wr = (bf16(*)[HD + 8])smem;                 // 32 x 520 bf16
    auto Wx = (bf16(*)[ED + 8])(smem + 33280);       // 32 x 264 bf16
    auto gl = (float(*)[33])(smem + 50176);          // 64 x 33 f32
    u32* go_lds = (u32*)(smem + 58624);

    const int wm   = wid & 3;        // m-fragment (batch rows 16*wm..)
    const int wn   = wid >> 2;       // n-fragment (cols 16*wn..), 0..1
    const int u0   = blk * 8;
    const int hi   = kh;             // which 8-chunk of the 32-K slice
    const int arow = 16 * wm + r16;  // batch row for A-frags
    const int brow = 16 * wn + r16;  // LDS row for B-frags

    const int eb   = (tid & 255) >> 2;   // 0..63
    const int j2   = (tid & 3) * 2;
    const int elen = len[eb];

    if (tid == 0) *go_lds = 0;
    u32 hp = 0;

    for (int phase = 0; phase < 2; ++phase) {
      const bf16* Wih  = phase ? WihD : WihE;
      const bf16* Whh  = phase ? WhhD : WhhE;
      const float* bsum = phase ? bsumD : bsumE;
      const bf16* Xall = phase ? decX : encX;

      for (int idx = tid; idx < 32 * HD; idx += 512) {
        int n = idx >> 9, k = idx & (HD - 1);
        Wr[n][k] = Whh[((n >> 3) * HD + u0 + (n & 7)) * HD + k];
      }
      for (int idx = tid; idx < 32 * ED; idx += 512) {
        int n = idx >> 8, k = idx & (ED - 1);
        Wx[n][k] = Wih[((n >> 3) * HD + u0 + (n & 7)) * ED + k];
      }
      const float bi0 = bsum[0 * HD + u0 + j2], bi1 = bsum[0 * HD + u0 + j2 + 1];
      const float bf0 = bsum[1 * HD + u0 + j2], bf1 = bsum[1 * HD + u0 + j2 + 1];
      const float bg0 = bsum[2 * HD + u0 + j2], bg1 = bsum[2 * HD + u0 + j2 + 1];
      const float bo0 = bsum[3 * HD + u0 + j2], bo1 = bsum[3 * HD + u0 + j2 + 1];
      float c0 = 0.f, c1 = 0.f;
      __syncthreads();

      for (int t = 0; t < ST; ++t) {
        const int step = phase * ST + t;
        u32* hxout = hx32 + (size_t)(step + 1) * SLOT32 + blk * 256;
        const bf16* xin = Xall + t * (NBAT * ED);

        // x-part first: overlaps peers' fire propagation
        f32x4 acc1 = {0.f, 0.f, 0.f, 0.f};
        #pragma unroll
        for (int kk = 0; kk < ED / 32; ++kk) {
          bf16x8 av = *(const bf16x8*)(xin + arow * ED + kk * 32 + kc);
          bf16x8 bv = *(const bf16x8*)(&Wx[brow][kk * 32 + kc]);
          acc1 = __builtin_amdgcn_mfma_f32_16x16x32_bf16(av, bv, acc1, 0, 0, 0);
        }

        // wait for h(step): wave0 fabric poll + LDS bounce
        if (step > 0) {
          if (wid == 0) {
            u32 f = __hip_atomic_load(&flags[lane], __ATOMIC_RELAXED,
                                      __HIP_MEMORY_SCOPE_AGENT);
            while (!__all((int)(f >= (u32)step))) {
              __builtin_amdgcn_s_sleep(1);
              f = __hip_atomic_load(&flags[lane], __ATOMIC_RELAXED,
                                    __HIP_MEMORY_SCOPE_AGENT);
            }
            if (lane == 0) {
              __hip_atomic_store(go_lds, (u32)step, __ATOMIC_RELAXED,
                                 __HIP_MEMORY_SCOPE_WORKGROUP);
              if (blk == 0)
                __hip_atomic_store(decgo, (u32)step, __ATOMIC_RELAXED,
                                   __HIP_MEMORY_SCOPE_AGENT);
            }
          } else {
            u32 g = __hip_atomic_load(go_lds, __ATOMIC_RELAXED,
                                      __HIP_MEMORY_SCOPE_WORKGROUP);
            while (g < (u32)step) {
              __builtin_amdgcn_s_sleep(1);
              g = __hip_atomic_load(go_lds, __ATOMIC_RELAXED,
                                    __HIP_MEMORY_SCOPE_WORKGROUP);
            }
          }
          __builtin_amdgcn_fence(__ATOMIC_ACQUIRE, "wavefront");
          __builtin_amdgcn_sched_barrier(0);
        }

        // h-part: 16 chunks, plain cached cold-miss loads
        const bf16* hbase = (const bf16*)(hx32 + (size_t)step * SLOT32);
        const bf16* hptr  = hbase + (size_t)hi * 512 + arow * 8;
        f32x4 accA = {0.f, 0.f, 0.f, 0.f};
        f32x4 accB = {0.f, 0.f, 0.f, 0.f};
        #pragma unroll
        for (int kk = 0; kk < 16; kk += 2) {
          bf16x8 a0 = *(const bf16x8*)(hptr + (size_t)kk * 2048);
          bf16x8 a1 = *(const bf16x8*)(hptr + (size_t)(kk + 1) * 2048);
          bf16x8 b0 = *(const bf16x8*)(&Wr[brow][kk * 32 + kc]);
          bf16x8 b1 = *(const bf16x8*)(&Wr[brow][(kk + 1) * 32 + kc]);
          accA = __builtin_amdgcn_mfma_f32_16x16x32_bf16(a0, b0, accA, 0, 0, 0);
          accB = __builtin_amdgcn_mfma_f32_16x16x32_bf16(a1, b1, accB, 0, 0, 0);
        }
        #pragma unroll
        for (int r = 0; r < 4; ++r)
          gl[16 * wm + kh * 4 + r][16 * wn + r16] = accA[r] + accB[r] + acc1[r];
        __syncthreads();

        // elementwise cell: 256 threads, two adjacent units each
        if (tid < 256) {
          float gi0 = gl[eb][j2]      + bi0, gi1 = gl[eb][j2 + 1]  + bi1;
          float gf0 = gl[eb][8 + j2]  + bf0, gf1 = gl[eb][9 + j2]  + bf1;
          float gg0 = gl[eb][16 + j2] + bg0, gg1 = gl[eb][17 + j2] + bg1;
          float go0 = gl[eb][24 + j2] + bo0, go1 = gl[eb][25 + j2] + bo1;
          bool upd = (phase == 1) || (t < elen);
          float cn0 = sigm(gf0) * c0 + sigm(gi0) * tanhf(gg0);
          float cn1 = sigm(gf1) * c1 + sigm(gi1) * tanhf(gg1);
          float hn0 = sigm(go0) * tanhf(cn0);
          float hn1 = sigm(go1) * tanhf(cn1);
          if (upd) {
            c0 = cn0; c1 = cn1;
            union { u32 u; bf16 h[2]; } pk;
            pk.h[0] = (bf16)hn0; pk.h[1] = (bf16)hn1;
            hp = pk.u;
          }
          __hip_atomic_store(&hxout[tid], hp, __ATOMIC_RELAXED,
                             __HIP_MEMORY_SCOPE_AGENT);
        }

        // drain bypass stores + gl-reuse guard, then fire (ALL steps)
        __syncthreads();
        if (tid == 0)
          __hip_atomic_store(&flags[blk], (u32)(step + 1), __ATOMIC_RELAXED,
                             __HIP_MEMORY_SCOPE_AGENT);
      }
    }

    // block0: confirm the final fire (flags=128) for the logits workers
    if (blk == 0 && wid == 0) {
      u32 f = __hip_atomic_load(&flags[lane], __ATOMIC_RELAXED,
                                __HIP_MEMORY_SCOPE_AGENT);
      while (!__all((int)(f >= (u32)(2 * ST)))) {
        __builtin_amdgcn_s_sleep(1);
        f = __hip_atomic_load(&flags[lane], __ATOMIC_RELAXED,
                              __HIP_MEMORY_SCOPE_AGENT);
      }
      if (lane == 0)
        __hip_atomic_store(decgo, (u32)(2 * ST), __ATOMIC_RELAXED,
                           __HIP_MEMORY_SCOPE_AGENT);
    }
  } else {
    // ================= logits worker =================
    auto Bs = (bf16(*)[HD + 8])smem;           // 128 x 520 bf16 (133120 B)
    u32* bgo = (u32*)(smem + 133120);
    const int lid = blk - NWORK;               // 0..191
    const int wm = wid & 3, wn = wid >> 2;
    const int arow = 16 * wm + r16;

    if (tid == 0) *bgo = 0;

    for (int nt = lid; nt < NTILES; nt += NLOG) {
      __syncthreads();  // previous tile fully consumed before restage
      for (int idx = tid; idx < 128 * (HD / 8); idx += 512) {
        int n = idx >> 6, k8 = (idx & 63) * 8;
        *(bf16x8*)&Bs[n][k8] =
            *(const bf16x8*)(WbL + (size_t)(nt * 128 + n) * HD + k8);
      }
      __syncthreads();

      for (int t = 0; t < ST; ++t) {
        const u32 target = (u32)(ST + 1 + t);
        if (wid == 0) {
          u32 v = __hip_atomic_load(decgo, __ATOMIC_RELAXED,
                                    __HIP_MEMORY_SCOPE_AGENT);
          while (v < target) {
            __builtin_amdgcn_s_sleep(64);   // ~1.7 us poll period: 30x less
            v = __hip_atomic_load(decgo, __ATOMIC_RELAXED,  // fabric traffic
                                  __HIP_MEMORY_SCOPE_AGENT);
          }
          if (lane == 0)
            __hip_atomic_store(bgo, v, __ATOMIC_RELAXED,
                               __HIP_MEMORY_SCOPE_WORKGROUP);
        } else {
          u32 g = __hip_atomic_load(bgo, __ATOMIC_RELAXED,
                                    __HIP_MEMORY_SCOPE_WORKGROUP);
          while (g < target) {
            __builtin_amdgcn_s_sleep(8);
            g = __hip_atomic_load(bgo, __ATOMIC_RELAXED,
                                  __HIP_MEMORY_SCOPE_WORKGROUP);
          }
        }
        __builtin_amdgcn_fence(__ATOMIC_ACQUIRE, "wavefront");
        __builtin_amdgcn_sched_barrier(0);

        // A = h(65+t) from the coherent slot (flag-gated -> fresh)
        const bf16* slotA = (const bf16*)(hx32 + (size_t)target * SLOT32);
        const bf16* aptr  = slotA + (size_t)kh * 512 + arow * 8;
        f32x4 acc[4];
        #pragma unroll
        for (int jj = 0; jj < 4; ++jj) acc[jj] = (f32x4){0.f, 0.f, 0.f, 0.f};
        #pragma unroll
        for (int kk = 0; kk < 16; ++kk) {
          bf16x8 av = *(const bf16x8*)(aptr + (size_t)kk * 2048);
          #pragma unroll
          for (int jj = 0; jj < 4; ++jj) {
            bf16x8 bv = *(const bf16x8*)(&Bs[64 * wn + 16 * jj + r16][kk * 32 + kc]);
            acc[jj] = __builtin_amdgcn_mfma_f32_16x16x32_bf16(av, bv, acc[jj], 0, 0, 0);
          }
        }
        #pragma unroll
        for (int jj = 0; jj < 4; ++jj) {
          int col = nt * 128 + 64 * wn + 16 * jj + r16;
          float bias = linb[col];
          #pragma unroll
          for (int r = 0; r < 4; ++r) {
            int b = 16 * wm + kh * 4 + r;
            out[((size_t)b * ST + t) * VO + col] = acc[jj][r] + bias;
          }
        }
      }
    }
  }
}

// ---------------- host ----------------

extern "C" void kernel_launch(void* const* d_in, const int* in_sizes, int n_in,
                              void* d_out, int out_size, void* d_ws, size_t ws_size,
                              hipStream_t stream) {
  const int*   toks = (const int*)d_in[0];
  const float* emb  = (const float*)d_in[1];
  const float* eWih = (const float*)d_in[2];
  const float* eWhh = (const float*)d_in[3];
  const float* ebih = (const float*)d_in[4];
  const float* ebhh = (const float*)d_in[5];
  const float* dWih = (const float*)d_in[6];
  const float* dWhh = (const float*)d_in[7];
  const float* dbih = (const float*)d_in[8];
  const float* dbhh = (const float*)d_in[9];
  const float* linW = (const float*)d_in[10];
  const float* linb = (const float*)d_in[11];
  float* out = (float*)d_out;

  char* ws = (char*)d_ws;
  size_t off = 0;
  auto alloc = [&](size_t bytes) {
    void* p = ws + off;
    off = (off + bytes + 255) & ~(size_t)255;
    return p;
  };
  bf16* encX  = (bf16*)alloc((size_t)ST * NBAT * ED * 2);
  bf16* decX  = (bf16*)alloc((size_t)ST * NBAT * ED * 2);
  bf16* WihEb = (bf16*)alloc((size_t)G4 * ED * 2);
  bf16* WhhEb = (bf16*)alloc((size_t)G4 * HD * 2);
  bf16* WihDb = (bf16*)alloc((size_t)G4 * ED * 2);
  bf16* WhhDb = (bf16*)alloc((size_t)G4 * HD * 2);
  bf16* WbL   = (bf16*)alloc((size_t)VO * HD * 2);
  float* bsumE = (float*)alloc(G4 * 4);
  float* bsumD = (float*)alloc(G4 * 4);
  u32*  hx    = (u32*)alloc((size_t)(2 * ST + 1) * SLOT32 * 4);  // 129 x 64 KB
  int*  len   = (int*)alloc(NBAT * 4);
  u32*  flags = (u32*)alloc(4096);
  u32*  decgo = flags + 64;   // own line (byte 256), inside memset region

  // slot 0 (h(0)=0) + flags/decgo must be clean every launch
  hipMemsetAsync(hx, 0, (size_t)SLOT32 * 4, stream);
  hipMemsetAsync(flags, 0, 4096, stream);

  k_lengths<<<1, 64, 0, stream>>>(toks, len);
  k_bias<<<(G4 + 255) / 256, 256, 0, stream>>>(ebih, ebhh, bsumE);
  k_bias<<<(G4 + 255) / 256, 256, 0, stream>>>(dbih, dbhh, bsumD);
  k_cast<<<(G4 * ED + 255) / 256, 256, 0, stream>>>(eWih, WihEb, G4 * ED);
  k_cast<<<(G4 * HD + 255) / 256, 256, 0, stream>>>(eWhh, WhhEb, G4 * HD);
  k_cast<<<(G4 * ED + 255) / 256, 256, 0, stream>>>(dWih, WihDb, G4 * ED);
  k_cast<<<(G4 * HD + 255) / 256, 256, 0, stream>>>(dWhh, WhhDb, G4 * HD);
  k_cast<<<(VO * HD + 255) / 256, 256, 0, stream>>>(linW, WbL, VO * HD);
  k_gather<<<(ST * NBAT * ED + 255) / 256, 256, 0, stream>>>(toks, emb, encX, decX);

  k_fused<<<NWORK + NLOG, 512, 0, stream>>>(
      encX, decX, WihEb, WhhEb, WihDb, WhhDb, bsumE, bsumD, len,
      WbL, linb, out, hx, flags, decgo);
}

// Round 13
// 793.652 us; speedup vs baseline: 1.0653x; 1.0653x over previous
//
#include <hip/hip_runtime.h>
#include <math.h>

// Problem constants
#define ST 64      // sequence length T
#define NBAT 64    // batch B
#define ED 256     // embedding dim E
#define HD 512     // hidden dim H
#define G4 2048    // 4*H
#define VO 32000   // vocab
#define NWORK 64               // recurrence blocks
#define NLOG 192               // logits worker blocks
#define NTILES (VO / 128)      // 250 vocab n-tiles
#define SLOT32 (NBAT * HD / 2) // u32s per h slot (64 KB)

typedef unsigned int u32;
typedef __bf16 bf16;
typedef bf16 bf16x8 __attribute__((ext_vector_type(8)));
typedef float f32x4 __attribute__((ext_vector_type(4)));

__device__ __forceinline__ float sigm(float x) { return 1.f / (1.f + expf(-x)); }

// ---------------- prep kernels ----------------

__global__ void k_lengths(const int* __restrict__ toks, int* __restrict__ len) {
  int b = threadIdx.x;
  if (b < NBAT) {
    int n = 0;
    for (int t = 0; t < ST; ++t) n += (toks[b * ST + t] != 0) ? 1 : 0;
    len[b] = n;
  }
}

// one launch: 4 weight casts + 2 bias sums (segment-dispatched, memory-bound)
#define SEG0 (G4 * ED)              // eWih
#define SEG1 (SEG0 + G4 * HD)       // eWhh
#define SEG2 (SEG1 + G4 * ED)       // dWih
#define SEG3 (SEG2 + G4 * HD)       // dWhh
#define SEG4 (SEG3 + G4)            // bsumE
#define SEG5 (SEG4 + G4)            // bsumD
__global__ void k_prep(const float* __restrict__ eWih, const float* __restrict__ eWhh,
                       const float* __restrict__ dWih, const float* __restrict__ dWhh,
                       const float* __restrict__ ebih, const float* __restrict__ ebhh,
                       const float* __restrict__ dbih, const float* __restrict__ dbhh,
                       bf16* __restrict__ WihEb, bf16* __restrict__ WhhEb,
                       bf16* __restrict__ WihDb, bf16* __restrict__ WhhDb,
                       float* __restrict__ bsumE, float* __restrict__ bsumD) {
  int i = blockIdx.x * blockDim.x + threadIdx.x;
  if (i < SEG0)      WihEb[i] = (bf16)eWih[i];
  else if (i < SEG1) WhhEb[i - SEG0] = (bf16)eWhh[i - SEG0];
  else if (i < SEG2) WihDb[i - SEG1] = (bf16)dWih[i - SEG1];
  else if (i < SEG3) WhhDb[i - SEG2] = (bf16)dWhh[i - SEG2];
  else if (i < SEG4) { int j = i - SEG3; bsumE[j] = ebih[j] + ebhh[j]; }
  else if (i < SEG5) { int j = i - SEG4; bsumD[j] = dbih[j] + dbhh[j]; }
}

// encX[t][b][e] = emb[toks[b][t]][e]; decX[t][b][e] = emb[t==0 ? 1 : toks[b][t-1]][e]
__global__ void k_gather(const int* __restrict__ toks, const float* __restrict__ emb,
                         bf16* __restrict__ encX, bf16* __restrict__ decX) {
  int i = blockIdx.x * blockDim.x + threadIdx.x;
  if (i >= ST * NBAT * ED) return;
  int e = i % ED;
  int tb = i / ED;
  int b = tb % NBAT;
  int t = tb / NBAT;
  int te = toks[b * ST + t];
  encX[i] = (bf16)emb[te * ED + e];
  int td = (t == 0) ? 1 : toks[b * ST + t - 1];
  decX[i] = (bf16)emb[td * ED + e];
}

// ---------------- fused persistent kernel ----------------
//
// 256 blocks, 1 per CU. Blocks 0..63: r10 recurrence (unchanged since r12).
// Blocks 64..255: logits workers on the otherwise-idle CUs.
//
// r13 worker changes (decoder-phase interference ~1.6 us/step in r11/r12):
//  - A-reads chunk-rotated by (kk+lid)&15: the 192-block herd lands on 16
//    distinct lines instead of all starting at chunk 0 (MSHR pileup at the
//    coherence point). Sum order is irrelevant.
//  - out-stores are NON-TEMPORAL: no L2 write-allocate -> no eviction of
//    the recurrence's cached x-tiles in the shared XCD L2s.
//  - B staged directly from f32 linW (inline cvt) -> WbL cast kernel gone.
__global__ __launch_bounds__(512, 2) void k_fused(
    const bf16* __restrict__ encX, const bf16* __restrict__ decX,
    const bf16* __restrict__ WihE, const bf16* __restrict__ WhhE,
    const bf16* __restrict__ WihD, const bf16* __restrict__ WhhD,
    const float* __restrict__ bsumE, const float* __restrict__ bsumD,
    const int* __restrict__ len,
    const float* __restrict__ linW, const float* __restrict__ linb,
    float* __restrict__ out,
    u32* __restrict__ hx32,    // [2*ST+1][NWORK][NBAT][8/2] per-step h slots
    u32* flags,                // [64] dense worker progress
    u32* decgo)                // [1] block0 broadcast of confirmed step
{
  __shared__ __align__(16) char smem[133632];

  const int tid  = threadIdx.x;
  const int lane = tid & 63;
  const int wid  = tid >> 6;
  const int blk  = blockIdx.x;
  const int r16  = lane & 15;
  const int kh   = lane >> 4;
  const int kc   = kh * 8;

  if (blk < NWORK) {
    // ================= recurrence block =================
    auto Wr = (bf16(*)[HD + 8])smem;                 // 32 x 520 bf16
    auto Wx = (bf16(*)[ED + 8])(smem + 33280);       // 32 x 264 bf16
    auto gl = (float(*)[33])(smem + 50176);          // 64 x 33 f32
    u32* go_lds = (u32*)(smem + 58624);

    const int wm   = wid & 3;        // m-fragment (batch rows 16*wm..)
    const int wn   = wid >> 2;       // n-fragment (cols 16*wn..), 0..1
    const int u0   = blk * 8;
    const int hi   = kh;             // which 8-chunk of the 32-K slice
    const int arow = 16 * wm + r16;  // batch row for A-frags
    const int brow = 16 * wn + r16;  // LDS row for B-frags

    const int eb   = (tid & 255) >> 2;   // 0..63
    const int j2   = (tid & 3) * 2;
    const int elen = len[eb];

    if (tid == 0) *go_lds = 0;
    u32 hp = 0;

    for (int phase = 0; phase < 2; ++phase) {
      const bf16* Wih  = phase ? WihD : WihE;
      const bf16* Whh  = phase ? WhhD : WhhE;
      const float* bsum = phase ? bsumD : bsumE;
      const bf16* Xall = phase ? decX : encX;

      for (int idx = tid; idx < 32 * HD; idx += 512) {
        int n = idx >> 9, k = idx & (HD - 1);
        Wr[n][k] = Whh[((n >> 3) * HD + u0 + (n & 7)) * HD + k];
      }
      for (int idx = tid; idx < 32 * ED; idx += 512) {
        int n = idx >> 8, k = idx & (ED - 1);
        Wx[n][k] = Wih[((n >> 3) * HD + u0 + (n & 7)) * ED + k];
      }
      const float bi0 = bsum[0 * HD + u0 + j2], bi1 = bsum[0 * HD + u0 + j2 + 1];
      const float bf0 = bsum[1 * HD + u0 + j2], bf1 = bsum[1 * HD + u0 + j2 + 1];
      const float bg0 = bsum[2 * HD + u0 + j2], bg1 = bsum[2 * HD + u0 + j2 + 1];
      const float bo0 = bsum[3 * HD + u0 + j2], bo1 = bsum[3 * HD + u0 + j2 + 1];
      float c0 = 0.f, c1 = 0.f;
      __syncthreads();

      for (int t = 0; t < ST; ++t) {
        const int step = phase * ST + t;
        u32* hxout = hx32 + (size_t)(step + 1) * SLOT32 + blk * 256;
        const bf16* xin = Xall + t * (NBAT * ED);

        // x-part first: overlaps peers' fire propagation
        f32x4 acc1 = {0.f, 0.f, 0.f, 0.f};
        #pragma unroll
        for (int kk = 0; kk < ED / 32; ++kk) {
          bf16x8 av = *(const bf16x8*)(xin + arow * ED + kk * 32 + kc);
          bf16x8 bv = *(const bf16x8*)(&Wx[brow][kk * 32 + kc]);
          acc1 = __builtin_amdgcn_mfma_f32_16x16x32_bf16(av, bv, acc1, 0, 0, 0);
        }

        // wait for h(step): wave0 fabric poll + LDS bounce
        if (step > 0) {
          if (wid == 0) {
            u32 f = __hip_atomic_load(&flags[lane], __ATOMIC_RELAXED,
                                      __HIP_MEMORY_SCOPE_AGENT);
            while (!__all((int)(f >= (u32)step))) {
              __builtin_amdgcn_s_sleep(1);
              f = __hip_atomic_load(&flags[lane], __ATOMIC_RELAXED,
                                    __HIP_MEMORY_SCOPE_AGENT);
            }
            if (lane == 0) {
              __hip_atomic_store(go_lds, (u32)step, __ATOMIC_RELAXED,
                                 __HIP_MEMORY_SCOPE_WORKGROUP);
              if (blk == 0)
                __hip_atomic_store(decgo, (u32)step, __ATOMIC_RELAXED,
                                   __HIP_MEMORY_SCOPE_AGENT);
            }
          } else {
            u32 g = __hip_atomic_load(go_lds, __ATOMIC_RELAXED,
                                      __HIP_MEMORY_SCOPE_WORKGROUP);
            while (g < (u32)step) {
              __builtin_amdgcn_s_sleep(1);
              g = __hip_atomic_load(go_lds, __ATOMIC_RELAXED,
                                    __HIP_MEMORY_SCOPE_WORKGROUP);
            }
          }
          __builtin_amdgcn_fence(__ATOMIC_ACQUIRE, "wavefront");
          __builtin_amdgcn_sched_barrier(0);
        }

        // h-part: 16 chunks, plain cached cold-miss loads
        const bf16* hbase = (const bf16*)(hx32 + (size_t)step * SLOT32);
        const bf16* hptr  = hbase + (size_t)hi * 512 + arow * 8;
        f32x4 accA = {0.f, 0.f, 0.f, 0.f};
        f32x4 accB = {0.f, 0.f, 0.f, 0.f};
        #pragma unroll
        for (int kk = 0; kk < 16; kk += 2) {
          bf16x8 a0 = *(const bf16x8*)(hptr + (size_t)kk * 2048);
          bf16x8 a1 = *(const bf16x8*)(hptr + (size_t)(kk + 1) * 2048);
          bf16x8 b0 = *(const bf16x8*)(&Wr[brow][kk * 32 + kc]);
          bf16x8 b1 = *(const bf16x8*)(&Wr[brow][(kk + 1) * 32 + kc]);
          accA = __builtin_amdgcn_mfma_f32_16x16x32_bf16(a0, b0, accA, 0, 0, 0);
          accB = __builtin_amdgcn_mfma_f32_16x16x32_bf16(a1, b1, accB, 0, 0, 0);
        }
        #pragma unroll
        for (int r = 0; r < 4; ++r)
          gl[16 * wm + kh * 4 + r][16 * wn + r16] = accA[r] + accB[r] + acc1[r];
        __syncthreads();

        // elementwise cell: 256 threads, two adjacent units each
        if (tid < 256) {
          float gi0 = gl[eb][j2]      + bi0, gi1 = gl[eb][j2 + 1]  + bi1;
          float gf0 = gl[eb][8 + j2]  + bf0, gf1 = gl[eb][9 + j2]  + bf1;
          float gg0 = gl[eb][16 + j2] + bg0, gg1 = gl[eb][17 + j2] + bg1;
          float go0 = gl[eb][24 + j2] + bo0, go1 = gl[eb][25 + j2] + bo1;
          bool upd = (phase == 1) || (t < elen);
          float cn0 = sigm(gf0) * c0 + sigm(gi0) * tanhf(gg0);
          float cn1 = sigm(gf1) * c1 + sigm(gi1) * tanhf(gg1);
          float hn0 = sigm(go0) * tanhf(cn0);
          float hn1 = sigm(go1) * tanhf(cn1);
          if (upd) {
            c0 = cn0; c1 = cn1;
            union { u32 u; bf16 h[2]; } pk;
            pk.h[0] = (bf16)hn0; pk.h[1] = (bf16)hn1;
            hp = pk.u;
          }
          __hip_atomic_store(&hxout[tid], hp, __ATOMIC_RELAXED,
                             __HIP_MEMORY_SCOPE_AGENT);
        }

        // drain bypass stores + gl-reuse guard, then fire (ALL steps)
        __syncthreads();
        if (tid == 0)
          __hip_atomic_store(&flags[blk], (u32)(step + 1), __ATOMIC_RELAXED,
                             __HIP_MEMORY_SCOPE_AGENT);
      }
    }

    // block0: confirm the final fire (flags=128) for the logits workers
    if (blk == 0 && wid == 0) {
      u32 f = __hip_atomic_load(&flags[lane], __ATOMIC_RELAXED,
                                __HIP_MEMORY_SCOPE_AGENT);
      while (!__all((int)(f >= (u32)(2 * ST)))) {
        __builtin_amdgcn_s_sleep(1);
        f = __hip_atomic_load(&flags[lane], __ATOMIC_RELAXED,
                              __HIP_MEMORY_SCOPE_AGENT);
      }
      if (lane == 0)
        __hip_atomic_store(decgo, (u32)(2 * ST), __ATOMIC_RELAXED,
                           __HIP_MEMORY_SCOPE_AGENT);
    }
  } else {
    // ================= logits worker =================
    auto Bs = (bf16(*)[HD + 8])smem;           // 128 x 520 bf16 (133120 B)
    u32* bgo = (u32*)(smem + 133120);
    const int lid = blk - NWORK;               // 0..191
    const int wm = wid & 3, wn = wid >> 2;
    const int arow = 16 * wm + r16;

    if (tid == 0) *bgo = 0;

    for (int nt = lid; nt < NTILES; nt += NLOG) {
      __syncthreads();  // previous tile fully consumed before restage
      // stage B from f32 linW with inline bf16 cvt
      for (int idx = tid; idx < 128 * (HD / 8); idx += 512) {
        int n = idx >> 6, k8 = (idx & 63) * 8;
        const float* bsrc = linW + (size_t)(nt * 128 + n) * HD + k8;
        f32x4 x0 = *(const f32x4*)bsrc;
        f32x4 x1 = *(const f32x4*)(bsrc + 4);
        bf16x8 bv;
        #pragma unroll
        for (int e = 0; e < 4; ++e) { bv[e] = (bf16)x0[e]; bv[4 + e] = (bf16)x1[e]; }
        *(bf16x8*)&Bs[n][k8] = bv;
      }
      __syncthreads();

      for (int t = 0; t < ST; ++t) {
        const u32 target = (u32)(ST + 1 + t);
        if (wid == 0) {
          u32 v = __hip_atomic_load(decgo, __ATOMIC_RELAXED,
                                    __HIP_MEMORY_SCOPE_AGENT);
          while (v < target) {
            __builtin_amdgcn_s_sleep(64);
            v = __hip_atomic_load(decgo, __ATOMIC_RELAXED,
                                  __HIP_MEMORY_SCOPE_AGENT);
          }
          if (lane == 0)
            __hip_atomic_store(bgo, v, __ATOMIC_RELAXED,
                               __HIP_MEMORY_SCOPE_WORKGROUP);
        } else {
          u32 g = __hip_atomic_load(bgo, __ATOMIC_RELAXED,
                                    __HIP_MEMORY_SCOPE_WORKGROUP);
          while (g < target) {
            __builtin_amdgcn_s_sleep(8);
            g = __hip_atomic_load(bgo, __ATOMIC_RELAXED,
                                  __HIP_MEMORY_SCOPE_WORKGROUP);
          }
        }
        __builtin_amdgcn_fence(__ATOMIC_ACQUIRE, "wavefront");
        __builtin_amdgcn_sched_barrier(0);

        // A = h(65+t); chunk order rotated by lid to spread the 192-block
        // herd across 16 distinct line groups (sum order irrelevant)
        const bf16* slotA = (const bf16*)(hx32 + (size_t)target * SLOT32);
        const bf16* aptr  = slotA + (size_t)kh * 512 + arow * 8;
        f32x4 acc[4];
        #pragma unroll
        for (int jj = 0; jj < 4; ++jj) acc[jj] = (f32x4){0.f, 0.f, 0.f, 0.f};
        #pragma unroll
        for (int kk = 0; kk < 16; ++kk) {
          int kks = (kk + lid) & 15;
          bf16x8 av = *(const bf16x8*)(aptr + (size_t)kks * 2048);
          #pragma unroll
          for (int jj = 0; jj < 4; ++jj) {
            bf16x8 bv = *(const bf16x8*)(&Bs[64 * wn + 16 * jj + r16][kks * 32 + kc]);
            acc[jj] = __builtin_amdgcn_mfma_f32_16x16x32_bf16(av, bv, acc[jj], 0, 0, 0);
          }
        }
        #pragma unroll
        for (int jj = 0; jj < 4; ++jj) {
          int col = nt * 128 + 64 * wn + 16 * jj + r16;
          float bias = linb[col];
          #pragma unroll
          for (int r = 0; r < 4; ++r) {
            int b = 16 * wm + kh * 4 + r;
            // non-temporal: don't pollute the shared XCD L2s
            __builtin_nontemporal_store(acc[jj][r] + bias,
                &out[((size_t)b * ST + t) * VO + col]);
          }
        }
      }
    }
  }
}

// ---------------- host ----------------

extern "C" void kernel_launch(void* const* d_in, const int* in_sizes, int n_in,
                              void* d_out, int out_size, void* d_ws, size_t ws_size,
                              hipStream_t stream) {
  const int*   toks = (const int*)d_in[0];
  const float* emb  = (const float*)d_in[1];
  const float* eWih = (const float*)d_in[2];
  const float* eWhh = (const float*)d_in[3];
  const float* ebih = (const float*)d_in[4];
  const float* ebhh = (const float*)d_in[5];
  const float* dWih = (const float*)d_in[6];
  const float* dWhh = (const float*)d_in[7];
  const float* dbih = (const float*)d_in[8];
  const float* dbhh = (const float*)d_in[9];
  const float* linW = (const float*)d_in[10];
  const float* linb = (const float*)d_in[11];
  float* out = (float*)d_out;

  char* ws = (char*)d_ws;
  size_t off = 0;
  auto alloc = [&](size_t bytes) {
    void* p = ws + off;
    off = (off + bytes + 255) & ~(size_t)255;
    return p;
  };
  bf16* encX  = (bf16*)alloc((size_t)ST * NBAT * ED * 2);
  bf16* decX  = (bf16*)alloc((size_t)ST * NBAT * ED * 2);
  bf16* WihEb = (bf16*)alloc((size_t)G4 * ED * 2);
  bf16* WhhEb = (bf16*)alloc((size_t)G4 * HD * 2);
  bf16* WihDb = (bf16*)alloc((size_t)G4 * ED * 2);
  bf16* WhhDb = (bf16*)alloc((size_t)G4 * HD * 2);
  float* bsumE = (float*)alloc(G4 * 4);
  float* bsumD = (float*)alloc(G4 * 4);
  u32*  hx    = (u32*)alloc((size_t)(2 * ST + 1) * SLOT32 * 4);  // 129 x 64 KB
  int*  len   = (int*)alloc(NBAT * 4);
  u32*  flags = (u32*)alloc(4096);
  u32*  decgo = flags + 64;   // own line (byte 256), inside memset region

  // slot 0 (h(0)=0) + flags/decgo must be clean every launch
  hipMemsetAsync(hx, 0, (size_t)SLOT32 * 4, stream);
  hipMemsetAsync(flags, 0, 4096, stream);

  k_lengths<<<1, 64, 0, stream>>>(toks, len);
  k_prep<<<(SEG5 + 255) / 256, 256, 0, stream>>>(
      eWih, eWhh, dWih, dWhh, ebih, ebhh, dbih, dbhh,
      WihEb, WhhEb, WihDb, WhhDb, bsumE, bsumD);
  k_gather<<<(ST * NBAT * ED + 255) / 256, 256, 0, stream>>>(toks, emb, encX, decX);

  k_fused<<<NWORK + NLOG, 512, 0, stream>>>(
      encX, decX, WihEb, WhhEb, WihDb, WhhDb, bsumE, bsumD, len,
      linW, linb, out, hx, flags, decgo);
}

// Round 14
// 752.343 us; speedup vs baseline: 1.1237x; 1.0549x over previous
//
#include <hip/hip_runtime.h>
#include <math.h>

// Problem constants
#define ST 64      // sequence length T
#define NBAT 64    // batch B
#define ED 256     // embedding dim E
#define HD 512     // hidden dim H
#define G4 2048    // 4*H
#define VO 32000   // vocab
#define NWORK 64               // recurrence blocks
#define NLOG 192               // logits worker blocks
#define NTILES (VO / 128)      // 250 vocab n-tiles
#define SLOT32 (NBAT * HD / 2) // u32s per h slot (64 KB)

typedef unsigned int u32;
typedef __bf16 bf16;
typedef bf16 bf16x8 __attribute__((ext_vector_type(8)));
typedef float f32x4 __attribute__((ext_vector_type(4)));

__device__ __forceinline__ float sigm(float x) { return 1.f / (1.f + expf(-x)); }

// ---------------- prep kernels ----------------

__global__ void k_lengths(const int* __restrict__ toks, int* __restrict__ len) {
  int b = threadIdx.x;
  if (b < NBAT) {
    int n = 0;
    for (int t = 0; t < ST; ++t) n += (toks[b * ST + t] != 0) ? 1 : 0;
    len[b] = n;
  }
}

// one launch: 4 weight casts + 2 bias sums (segment-dispatched, memory-bound)
#define SEG0 (G4 * ED)              // eWih
#define SEG1 (SEG0 + G4 * HD)       // eWhh
#define SEG2 (SEG1 + G4 * ED)       // dWih
#define SEG3 (SEG2 + G4 * HD)       // dWhh
#define SEG4 (SEG3 + G4)            // bsumE
#define SEG5 (SEG4 + G4)            // bsumD
__global__ void k_prep(const float* __restrict__ eWih, const float* __restrict__ eWhh,
                       const float* __restrict__ dWih, const float* __restrict__ dWhh,
                       const float* __restrict__ ebih, const float* __restrict__ ebhh,
                       const float* __restrict__ dbih, const float* __restrict__ dbhh,
                       bf16* __restrict__ WihEb, bf16* __restrict__ WhhEb,
                       bf16* __restrict__ WihDb, bf16* __restrict__ WhhDb,
                       float* __restrict__ bsumE, float* __restrict__ bsumD) {
  int i = blockIdx.x * blockDim.x + threadIdx.x;
  if (i < SEG0)      WihEb[i] = (bf16)eWih[i];
  else if (i < SEG1) WhhEb[i - SEG0] = (bf16)eWhh[i - SEG0];
  else if (i < SEG2) WihDb[i - SEG1] = (bf16)dWih[i - SEG1];
  else if (i < SEG3) WhhDb[i - SEG2] = (bf16)dWhh[i - SEG2];
  else if (i < SEG4) { int j = i - SEG3; bsumE[j] = ebih[j] + ebhh[j]; }
  else if (i < SEG5) { int j = i - SEG4; bsumD[j] = dbih[j] + dbhh[j]; }
}

// encX[t][b][e] = emb[toks[b][t]][e]; decX[t][b][e] = emb[t==0 ? 1 : toks[b][t-1]][e]
__global__ void k_gather(const int* __restrict__ toks, const float* __restrict__ emb,
                         bf16* __restrict__ encX, bf16* __restrict__ decX) {
  int i = blockIdx.x * blockDim.x + threadIdx.x;
  if (i >= ST * NBAT * ED) return;
  int e = i % ED;
  int tb = i / ED;
  int b = tb % NBAT;
  int t = tb / NBAT;
  int te = toks[b * ST + t];
  encX[i] = (bf16)emb[te * ED + e];
  int td = (t == 0) ? 1 : toks[b * ST + t - 1];
  decX[i] = (bf16)emb[td * ED + e];
}

// ---------------- fused persistent kernel ----------------
//
// 256 blocks, 1 per CU. Blocks 0..63: recurrence. Blocks 64..255: logits
// workers on the otherwise-idle CUs.
//
// r14 recurrence change -- SPLIT-FIRE (barrier2 removed from fire path):
//   gl is double-buffered by step parity (no reuse guard needed; step+2's
//   gl[par] rewrite is gated behind fire(step+2), which requires step+1's
//   cells complete). After barrier1 (gl ready), each of the 4 h-storing
//   waves independently: cell -> bypass store -> s_waitcnt vmcnt(0) (OWN
//   stores only) -> LDS monotonic counter bump. Wave 3 spins on the
//   counter (LDS, ns-scale) and fires flags[blk] the instant all 4
//   quarters are acked. Waves 4..7 never rendezvous -- straight to step+1.
//   flag >= v still implies all 256 h-words acked at the coherence point.
// r14 worker change: revert non-temporal out stores (r13: +146 MB
//   partial-line write amplification) to plain stores.
__global__ __launch_bounds__(512, 2) void k_fused(
    const bf16* __restrict__ encX, const bf16* __restrict__ decX,
    const bf16* __restrict__ WihE, const bf16* __restrict__ WhhE,
    const bf16* __restrict__ WihD, const bf16* __restrict__ WhhD,
    const float* __restrict__ bsumE, const float* __restrict__ bsumD,
    const int* __restrict__ len,
    const float* __restrict__ linW, const float* __restrict__ linb,
    float* __restrict__ out,
    u32* __restrict__ hx32,    // [2*ST+1][NWORK][NBAT][8/2] per-step h slots
    u32* flags,                // [64] dense worker progress
    u32* decgo)                // [1] block0 broadcast of confirmed step
{
  __shared__ __align__(16) char smem[133632];

  const int tid  = threadIdx.x;
  const int lane = tid & 63;
  const int wid  = tid >> 6;
  const int blk  = blockIdx.x;
  const int r16  = lane & 15;
  const int kh   = lane >> 4;
  const int kc   = kh * 8;

  if (blk < NWORK) {
    // ================= recurrence block =================
    auto Wr  = (bf16(*)[HD + 8])smem;                 // 32 x 520 bf16 -> 33280
    auto Wx  = (bf16(*)[ED + 8])(smem + 33280);       // 32 x 264 bf16 -> +16896
    auto gl  = (float(*)[64][33])(smem + 50176);      // 2 x 64 x 33 f32 -> +16896
    u32* go_lds = (u32*)(smem + 67072);
    u32* dcnt   = (u32*)(smem + 67076);               // monotonic wave-done count

    const int wm   = wid & 3;        // m-fragment (batch rows 16*wm..)
    const int wn   = wid >> 2;       // n-fragment (cols 16*wn..), 0..1
    const int u0   = blk * 8;
    const int hi   = kh;             // which 8-chunk of the 32-K slice
    const int arow = 16 * wm + r16;  // batch row for A-frags
    const int brow = 16 * wn + r16;  // LDS row for B-frags

    const int eb   = (tid & 255) >> 2;   // 0..63
    const int j2   = (tid & 3) * 2;
    const int elen = len[eb];

    if (tid == 0) { *go_lds = 0; *dcnt = 0; }
    u32 hp = 0;

    for (int phase = 0; phase < 2; ++phase) {
      const bf16* Wih  = phase ? WihD : WihE;
      const bf16* Whh  = phase ? WhhD : WhhE;
      const float* bsum = phase ? bsumD : bsumE;
      const bf16* Xall = phase ? decX : encX;

      for (int idx = tid; idx < 32 * HD; idx += 512) {
        int n = idx >> 9, k = idx & (HD - 1);
        Wr[n][k] = Whh[((n >> 3) * HD + u0 + (n & 7)) * HD + k];
      }
      for (int idx = tid; idx < 32 * ED; idx += 512) {
        int n = idx >> 8, k = idx & (ED - 1);
        Wx[n][k] = Wih[((n >> 3) * HD + u0 + (n & 7)) * ED + k];
      }
      const float bi0 = bsum[0 * HD + u0 + j2], bi1 = bsum[0 * HD + u0 + j2 + 1];
      const float bf0 = bsum[1 * HD + u0 + j2], bf1 = bsum[1 * HD + u0 + j2 + 1];
      const float bg0 = bsum[2 * HD + u0 + j2], bg1 = bsum[2 * HD + u0 + j2 + 1];
      const float bo0 = bsum[3 * HD + u0 + j2], bo1 = bsum[3 * HD + u0 + j2 + 1];
      float c0 = 0.f, c1 = 0.f;
      __syncthreads();  // weights + go_lds/dcnt published

      for (int t = 0; t < ST; ++t) {
        const int step = phase * ST + t;
        const int par  = step & 1;
        u32* hxout = hx32 + (size_t)(step + 1) * SLOT32 + blk * 256;
        const bf16* xin = Xall + t * (NBAT * ED);

        // x-part first: overlaps peers' fire propagation
        f32x4 acc1 = {0.f, 0.f, 0.f, 0.f};
        #pragma unroll
        for (int kk = 0; kk < ED / 32; ++kk) {
          bf16x8 av = *(const bf16x8*)(xin + arow * ED + kk * 32 + kc);
          bf16x8 bv = *(const bf16x8*)(&Wx[brow][kk * 32 + kc]);
          acc1 = __builtin_amdgcn_mfma_f32_16x16x32_bf16(av, bv, acc1, 0, 0, 0);
        }

        // wait for h(step): wave0 fabric poll + LDS bounce
        if (step > 0) {
          if (wid == 0) {
            u32 f = __hip_atomic_load(&flags[lane], __ATOMIC_RELAXED,
                                      __HIP_MEMORY_SCOPE_AGENT);
            while (!__all((int)(f >= (u32)step))) {
              __builtin_amdgcn_s_sleep(1);
              f = __hip_atomic_load(&flags[lane], __ATOMIC_RELAXED,
                                    __HIP_MEMORY_SCOPE_AGENT);
            }
            if (lane == 0) {
              __hip_atomic_store(go_lds, (u32)step, __ATOMIC_RELAXED,
                                 __HIP_MEMORY_SCOPE_WORKGROUP);
              if (blk == 0)
                __hip_atomic_store(decgo, (u32)step, __ATOMIC_RELAXED,
                                   __HIP_MEMORY_SCOPE_AGENT);
            }
          } else {
            u32 g = __hip_atomic_load(go_lds, __ATOMIC_RELAXED,
                                      __HIP_MEMORY_SCOPE_WORKGROUP);
            while (g < (u32)step) {
              __builtin_amdgcn_s_sleep(1);
              g = __hip_atomic_load(go_lds, __ATOMIC_RELAXED,
                                    __HIP_MEMORY_SCOPE_WORKGROUP);
            }
          }
          __builtin_amdgcn_fence(__ATOMIC_ACQUIRE, "wavefront");
          __builtin_amdgcn_sched_barrier(0);
        }

        // h-part: 16 chunks, plain cached cold-miss loads
        const bf16* hbase = (const bf16*)(hx32 + (size_t)step * SLOT32);
        const bf16* hptr  = hbase + (size_t)hi * 512 + arow * 8;
        f32x4 accA = {0.f, 0.f, 0.f, 0.f};
        f32x4 accB = {0.f, 0.f, 0.f, 0.f};
        #pragma unroll
        for (int kk = 0; kk < 16; kk += 2) {
          bf16x8 a0 = *(const bf16x8*)(hptr + (size_t)kk * 2048);
          bf16x8 a1 = *(const bf16x8*)(hptr + (size_t)(kk + 1) * 2048);
          bf16x8 b0 = *(const bf16x8*)(&Wr[brow][kk * 32 + kc]);
          bf16x8 b1 = *(const bf16x8*)(&Wr[brow][(kk + 1) * 32 + kc]);
          accA = __builtin_amdgcn_mfma_f32_16x16x32_bf16(a0, b0, accA, 0, 0, 0);
          accB = __builtin_amdgcn_mfma_f32_16x16x32_bf16(a1, b1, accB, 0, 0, 0);
        }
        #pragma unroll
        for (int r = 0; r < 4; ++r)
          gl[par][16 * wm + kh * 4 + r][16 * wn + r16] = accA[r] + accB[r] + acc1[r];
        __syncthreads();  // barrier1: gl[par] ready

        // cell + split-fire: waves 0-3 only; waves 4-7 go straight to t+1
        if (tid < 256) {
          float gi0 = gl[par][eb][j2]      + bi0, gi1 = gl[par][eb][j2 + 1]  + bi1;
          float gf0 = gl[par][eb][8 + j2]  + bf0, gf1 = gl[par][eb][9 + j2]  + bf1;
          float gg0 = gl[par][eb][16 + j2] + bg0, gg1 = gl[par][eb][17 + j2] + bg1;
          float go0 = gl[par][eb][24 + j2] + bo0, go1 = gl[par][eb][25 + j2] + bo1;
          bool upd = (phase == 1) || (t < elen);
          float cn0 = sigm(gf0) * c0 + sigm(gi0) * tanhf(gg0);
          float cn1 = sigm(gf1) * c1 + sigm(gi1) * tanhf(gg1);
          float hn0 = sigm(go0) * tanhf(cn0);
          float hn1 = sigm(go1) * tanhf(cn1);
          if (upd) {
            c0 = cn0; c1 = cn1;
            union { u32 u; bf16 h[2]; } pk;
            pk.h[0] = (bf16)hn0; pk.h[1] = (bf16)hn1;
            hp = pk.u;
          }
          __hip_atomic_store(&hxout[tid], hp, __ATOMIC_RELAXED,
                             __HIP_MEMORY_SCOPE_AGENT);
          // drain OWN wave's bypass stores (acks at coherence point)
          asm volatile("s_waitcnt vmcnt(0)" ::: "memory");
          __builtin_amdgcn_sched_barrier(0);
          if (lane == 0)
            __hip_atomic_fetch_add(dcnt, 1u, __ATOMIC_RELAXED,
                                   __HIP_MEMORY_SCOPE_WORKGROUP);
          if (wid == 3) {  // firer wave: spin LDS counter, then fire
            u32 c = __hip_atomic_load(dcnt, __ATOMIC_RELAXED,
                                      __HIP_MEMORY_SCOPE_WORKGROUP);
            while (c < 4u * (u32)(step + 1)) {
              __builtin_amdgcn_s_sleep(1);
              c = __hip_atomic_load(dcnt, __ATOMIC_RELAXED,
                                    __HIP_MEMORY_SCOPE_WORKGROUP);
            }
            if (lane == 0)
              __hip_atomic_store(&flags[blk], (u32)(step + 1), __ATOMIC_RELAXED,
                                 __HIP_MEMORY_SCOPE_AGENT);
          }
        }
      }
    }

    // block0: confirm the final fire (flags=128) for the logits workers
    if (blk == 0 && wid == 0) {
      u32 f = __hip_atomic_load(&flags[lane], __ATOMIC_RELAXED,
                                __HIP_MEMORY_SCOPE_AGENT);
      while (!__all((int)(f >= (u32)(2 * ST)))) {
        __builtin_amdgcn_s_sleep(1);
        f = __hip_atomic_load(&flags[lane], __ATOMIC_RELAXED,
                              __HIP_MEMORY_SCOPE_AGENT);
      }
      if (lane == 0)
        __hip_atomic_store(decgo, (u32)(2 * ST), __ATOMIC_RELAXED,
                           __HIP_MEMORY_SCOPE_AGENT);
    }
  } else {
    // ================= logits worker =================
    auto Bs = (bf16(*)[HD + 8])smem;           // 128 x 520 bf16 (133120 B)
    u32* bgo = (u32*)(smem + 133120);
    const int lid = blk - NWORK;               // 0..191
    const int wm = wid & 3, wn = wid >> 2;
    const int arow = 16 * wm + r16;

    if (tid == 0) *bgo = 0;

    for (int nt = lid; nt < NTILES; nt += NLOG) {
      __syncthreads();  // previous tile fully consumed before restage
      // stage B from f32 linW with inline bf16 cvt
      for (int idx = tid; idx < 128 * (HD / 8); idx += 512) {
        int n = idx >> 6, k8 = (idx & 63) * 8;
        const float* bsrc = linW + (size_t)(nt * 128 + n) * HD + k8;
        f32x4 x0 = *(const f32x4*)bsrc;
        f32x4 x1 = *(const f32x4*)(bsrc + 4);
        bf16x8 bv;
        #pragma unroll
        for (int e = 0; e < 4; ++e) { bv[e] = (bf16)x0[e]; bv[4 + e] = (bf16)x1[e]; }
        *(bf16x8*)&Bs[n][k8] = bv;
      }
      __syncthreads();

      for (int t = 0; t < ST; ++t) {
        const u32 target = (u32)(ST + 1 + t);
        if (wid == 0) {
          u32 v = __hip_atomic_load(decgo, __ATOMIC_RELAXED,
                                    __HIP_MEMORY_SCOPE_AGENT);
          while (v < target) {
            __builtin_amdgcn_s_sleep(64);
            v = __hip_atomic_load(decgo, __ATOMIC_RELAXED,
                                  __HIP_MEMORY_SCOPE_AGENT);
          }
          if (lane == 0)
            __hip_atomic_store(bgo, v, __ATOMIC_RELAXED,
                               __HIP_MEMORY_SCOPE_WORKGROUP);
        } else {
          u32 g = __hip_atomic_load(bgo, __ATOMIC_RELAXED,
                                    __HIP_MEMORY_SCOPE_WORKGROUP);
          while (g < target) {
            __builtin_amdgcn_s_sleep(8);
            g = __hip_atomic_load(bgo, __ATOMIC_RELAXED,
                                  __HIP_MEMORY_SCOPE_WORKGROUP);
          }
        }
        __builtin_amdgcn_fence(__ATOMIC_ACQUIRE, "wavefront");
        __builtin_amdgcn_sched_barrier(0);

        // A = h(65+t); chunk order rotated by lid to spread the herd
        const bf16* slotA = (const bf16*)(hx32 + (size_t)target * SLOT32);
        const bf16* aptr  = slotA + (size_t)kh * 512 + arow * 8;
        f32x4 acc[4];
        #pragma unroll
        for (int jj = 0; jj < 4; ++jj) acc[jj] = (f32x4){0.f, 0.f, 0.f, 0.f};
        #pragma unroll
        for (int kk = 0; kk < 16; ++kk) {
          int kks = (kk + lid) & 15;
          bf16x8 av = *(const bf16x8*)(aptr + (size_t)kks * 2048);
          #pragma unroll
          for (int jj = 0; jj < 4; ++jj) {
            bf16x8 bv = *(const bf16x8*)(&Bs[64 * wn + 16 * jj + r16][kks * 32 + kc]);
            acc[jj] = __builtin_amdgcn_mfma_f32_16x16x32_bf16(av, bv, acc[jj], 0, 0, 0);
          }
        }
        #pragma unroll
        for (int jj = 0; jj < 4; ++jj) {
          int col = nt * 128 + 64 * wn + 16 * jj + r16;
          float bias = linb[col];
          #pragma unroll
          for (int r = 0; r < 4; ++r) {
            int b = 16 * wm + kh * 4 + r;
            out[((size_t)b * ST + t) * VO + col] = acc[jj][r] + bias;
          }
        }
      }
    }
  }
}

// ---------------- host ----------------

extern "C" void kernel_launch(void* const* d_in, const int* in_sizes, int n_in,
                              void* d_out, int out_size, void* d_ws, size_t ws_size,
                              hipStream_t stream) {
  const int*   toks = (const int*)d_in[0];
  const float* emb  = (const float*)d_in[1];
  const float* eWih = (const float*)d_in[2];
  const float* eWhh = (const float*)d_in[3];
  const float* ebih = (const float*)d_in[4];
  const float* ebhh = (const float*)d_in[5];
  const float* dWih = (const float*)d_in[6];
  const float* dWhh = (const float*)d_in[7];
  const float* dbih = (const float*)d_in[8];
  const float* dbhh = (const float*)d_in[9];
  const float* linW = (const float*)d_in[10];
  const float* linb = (const float*)d_in[11];
  float* out = (float*)d_out;

  char* ws = (char*)d_ws;
  size_t off = 0;
  auto alloc = [&](size_t bytes) {
    void* p = ws + off;
    off = (off + bytes + 255) & ~(size_t)255;
    return p;
  };
  bf16* encX  = (bf16*)alloc((size_t)ST * NBAT * ED * 2);
  bf16* decX  = (bf16*)alloc((size_t)ST * NBAT * ED * 2);
  bf16* WihEb = (bf16*)alloc((size_t)G4 * ED * 2);
  bf16* WhhEb = (bf16*)alloc((size_t)G4 * HD * 2);
  bf16* WihDb = (bf16*)alloc((size_t)G4 * ED * 2);
  bf16* WhhDb = (bf16*)alloc((size_t)G4 * HD * 2);
  float* bsumE = (float*)alloc(G4 * 4);
  float* bsumD = (float*)alloc(G4 * 4);
  u32*  hx    = (u32*)alloc((size_t)(2 * ST + 1) * SLOT32 * 4);  // 129 x 64 KB
  int*  len   = (int*)alloc(NBAT * 4);
  u32*  flags = (u32*)alloc(4096);
  u32*  decgo = flags + 64;   // own line (byte 256), inside memset region

  // slot 0 (h(0)=0) + flags/decgo must be clean every launch
  hipMemsetAsync(hx, 0, (size_t)SLOT32 * 4, stream);
  hipMemsetAsync(flags, 0, 4096, stream);

  k_lengths<<<1, 64, 0, stream>>>(toks, len);
  k_prep<<<(SEG5 + 255) / 256, 256, 0, stream>>>(
      eWih, eWhh, dWih, dWhh, ebih, ebhh, dbih, dbhh,
      WihEb, WhhEb, WihDb, WhhDb, bsumE, bsumD);
  k_gather<<<(ST * NBAT * ED + 255) / 256, 256, 0, stream>>>(toks, emb, encX, decX);

  k_fused<<<NWORK + NLOG, 512, 0, stream>>>(
      encX, decX, WihEb, WhhEb, WihDb, WhhDb, bsumE, bsumD, len,
      linW, linb, out, hx, flags, decgo);
}